// Round 14
// baseline (1342.258 us; speedup 1.0000x reference)
//
#include <hip/hip_runtime.h>
#include <hip/hip_fp16.h>

// GraphSAGE 3-layer, N=1M, E=16M, widths 1->4->4->2.
// R3: device atomics limit. R4: bucketing. R5: counting sort + register agg.
// R7: LDS fill-and-flush scatter. R9: fp16 gather tables. R10: L2-resident
// gathers via src-quarter sweeps. R11: scatter occupancy 2 blk/CU (623us).
// R12 (1024-bin quarter-sort) REGRESSED (681us) -> reverted.
// R13 (this): R11 + drop LDS srun staging in agg passes - after the sort,
// each thread's record run is private and contiguous (one cache line);
// L1/L2 serve it directly, the LDS copy + barrier was pure overhead.

#define NBUCK 4096
#define CAP   4608            // avg 4096 edges/bucket, +8 sigma headroom
#define SRCM  0xFFFFFu        // 20-bit src mask (N <= 2^20)
#define DEPTH 4               // staging slots per bucket (16 B group)

__device__ __forceinline__ ushort4 pack_h4(float4 f)
{
    ushort4 r;
    r.x = __half_as_ushort(__float2half_rn(f.x));
    r.y = __half_as_ushort(__float2half_rn(f.y));
    r.z = __half_as_ushort(__float2half_rn(f.z));
    r.w = __half_as_ushort(__float2half_rn(f.w));
    return r;
}

__device__ __forceinline__ float4 unpack_h4(ushort4 v)
{
    return make_float4(__half2float(__ushort_as_half(v.x)),
                       __half2float(__ushort_as_half(v.y)),
                       __half2float(__ushort_as_half(v.z)),
                       __half2float(__ushort_as_half(v.w)));
}

__global__ __launch_bounds__(256) void init_cursor(unsigned* __restrict__ cursor)
{
    int b = blockIdx.x * blockDim.x + threadIdx.x;
    if (b < NBUCK) cursor[b] = (unsigned)b * CAP;
}

// LDS fill-and-flush scatter (R11): 80 KB LDS -> 2 blocks/CU.
__global__ __launch_bounds__(1024) void scatter_staged(
    const int* __restrict__ ei,
    unsigned* __restrict__ gcur,
    unsigned* __restrict__ bucket,
    long long E, long long chunk)
{
    __shared__ unsigned stage[NBUCK * DEPTH];  // 64 KB
    __shared__ unsigned cnt[NBUCK];            // 16 KB
    const int t = threadIdx.x;
    const long long beg = (long long)blockIdx.x * chunk;
    const long long end = min(E, beg + chunk);

    for (int i = t; i < NBUCK; i += 1024) cnt[i] = 0;
    __syncthreads();

    for (long long base = beg; base < end; base += 4096) {
        unsigned rec[4], bk[4], pos[4];
        int nv = 0;
        long long i = base + (long long)t * 4;
        if (i + 4 <= end) {
            int4 s4 = *reinterpret_cast<const int4*>(ei + i);
            int4 d4 = *reinterpret_cast<const int4*>(ei + E + i);
            rec[0] = (unsigned)s4.x | (((unsigned)d4.x & 255u) << 20); bk[0] = (unsigned)d4.x >> 8;
            rec[1] = (unsigned)s4.y | (((unsigned)d4.y & 255u) << 20); bk[1] = (unsigned)d4.y >> 8;
            rec[2] = (unsigned)s4.z | (((unsigned)d4.z & 255u) << 20); bk[2] = (unsigned)d4.z >> 8;
            rec[3] = (unsigned)s4.w | (((unsigned)d4.w & 255u) << 20); bk[3] = (unsigned)d4.w >> 8;
            nv = 4;
        } else {
            for (long long j = i; j < end && nv < 4; ++j) {
                unsigned s = (unsigned)ei[j];
                unsigned d = (unsigned)ei[E + j];
                rec[nv] = s | ((d & 255u) << 20);
                bk[nv] = d >> 8;
                ++nv;
            }
        }
        for (int k = 0; k < nv; ++k) pos[k] = atomicAdd(&cnt[bk[k]], 1u);
        __syncthreads();
        for (int k = 0; k < nv; ++k)
            if (pos[k] < DEPTH) stage[bk[k] * DEPTH + pos[k]] = rec[k];
        __syncthreads();
        // flush full buffers: one uint4 (16 B, aligned) per group
        for (int bb = t; bb < NBUCK; bb += 1024) {
            unsigned c = cnt[bb];
            if (c >= DEPTH) {
                unsigned gb = atomicAdd(&gcur[bb], DEPTH);
                unsigned lim = (unsigned)(bb + 1) * CAP;
                if ((gb & 3u) == 0u && gb + DEPTH <= lim) {
                    *reinterpret_cast<uint4*>(bucket + gb) =
                        *reinterpret_cast<const uint4*>(stage + bb * DEPTH);
                } else {
#pragma unroll
                    for (int k = 0; k < DEPTH; ++k)
                        if (gb + k < lim) bucket[gb + k] = stage[bb * DEPTH + k];
                }
                cnt[bb] = 0;
            }
        }
        __syncthreads();
        // round 2: records that overflowed the buffer this batch
        for (int k = 0; k < nv; ++k) {
            if (pos[k] >= DEPTH) {
                unsigned p2 = atomicAdd(&cnt[bk[k]], 1u);
                if (p2 < DEPTH) stage[bk[k] * DEPTH + p2] = rec[k];
                else {
                    unsigned gb = atomicAdd(&gcur[bk[k]], 1u);
                    if (gb < (unsigned)(bk[k] + 1) * CAP) bucket[gb] = rec[k];
                }
            }
        }
        __syncthreads();
    }
    // drain partial buffers
    for (int bb = t; bb < NBUCK; bb += 1024) {
        unsigned c = min(cnt[bb], (unsigned)DEPTH);
        if (c) {
            unsigned gb = atomicAdd(&gcur[bb], c);
            unsigned lim = (unsigned)(bb + 1) * CAP;
            for (unsigned k = 0; k < c; ++k)
                if (gb + k < lim) bucket[gb + k] = stage[bb * DEPTH + k];
        }
    }
}

// Fused: per-bucket 256-bin counting sort by dst + layer-1 (R11 version).
template <bool EMIT16>
__global__ __launch_bounds__(256) void sort_l1(
    unsigned* __restrict__ bucket,
    const unsigned* __restrict__ cursor,
    unsigned* __restrict__ meta,         // [N]: lstart | cnt<<16
    const float* __restrict__ x,
    const float* __restrict__ W1l, const float* __restrict__ b1,
    const float* __restrict__ W1r,
    float* __restrict__ invout, float4* __restrict__ h1,
    ushort4* __restrict__ h1h, int N)
{
    __shared__ unsigned recA[CAP];
    __shared__ unsigned recB[CAP];
    __shared__ unsigned hist[256], pref[256], curs[256];
    const int t = threadIdx.x;
    const unsigned b = blockIdx.x;
    const unsigned base = b * CAP;
    const unsigned cnt = min(cursor[b] - base, (unsigned)CAP);

    hist[t] = 0;
    __syncthreads();
    for (unsigned i = t; i < cnt; i += 256) {
        unsigned r = bucket[base + i];
        recA[i] = r;
        atomicAdd(&hist[r >> 20], 1u);
    }
    __syncthreads();
    unsigned v = hist[t];
    pref[t] = v;
    __syncthreads();
    for (int off = 1; off < 256; off <<= 1) {
        unsigned u = (t >= off) ? pref[t - off] : 0u;
        __syncthreads();
        pref[t] += u;
        __syncthreads();
    }
    unsigned excl = pref[t] - v;
    curs[t] = excl;
    __syncthreads();
    for (unsigned i = t; i < cnt; i += 256) {
        unsigned r = recA[i];
        unsigned pos = atomicAdd(&curs[r >> 20], 1u);
        recB[pos] = r & SRCM;
    }
    __syncthreads();
    for (unsigned i = t; i < cnt; i += 256)
        bucket[base + i] = recB[i];

    int dst = (int)(b * 256u) + t;
    if (dst >= N) return;
    meta[dst] = excl | (v << 16);

    float sum = 0.0f;                        // 4-deep unrolled x-gather
    unsigned j = 0;
    for (; j + 4 <= v; j += 4) {
        unsigned s0 = recB[excl + j + 0];
        unsigned s1 = recB[excl + j + 1];
        unsigned s2 = recB[excl + j + 2];
        unsigned s3 = recB[excl + j + 3];
        sum += x[s0] + x[s1] + x[s2] + x[s3];
    }
    for (; j < v; ++j) sum += x[recB[excl + j]];

    float iv = 1.0f / fmaxf((float)v, 1.0f);
    invout[dst] = iv;
    float a = sum * iv;
    float xv = x[dst];
    float4 h;
    h.x = fmaxf(a * W1l[0] + b1[0] + xv * W1r[0], 0.0f);
    h.y = fmaxf(a * W1l[1] + b1[1] + xv * W1r[1], 0.0f);
    h.z = fmaxf(a * W1l[2] + b1[2] + xv * W1r[2], 0.0f);
    h.w = fmaxf(a * W1l[3] + b1[3] + xv * W1r[3], 0.0f);
    h1[dst] = h;
    if (EMIT16) h1h[dst] = pack_h4(h);
}

// fp32 run gather from global (non-fp16 fallback)
__device__ __forceinline__ float4 run_sum4(
    const unsigned* __restrict__ srtd, unsigned idx, unsigned c,
    const float4* __restrict__ feat)
{
    float a0 = 0, a1 = 0, a2 = 0, a3 = 0;
    unsigned j = 0;
    for (; j + 4 <= c; j += 4) {
        unsigned s0 = srtd[idx + j + 0];
        unsigned s1 = srtd[idx + j + 1];
        unsigned s2 = srtd[idx + j + 2];
        unsigned s3 = srtd[idx + j + 3];
        float4 f0 = feat[s0];
        float4 f1 = feat[s1];
        float4 f2 = feat[s2];
        float4 f3 = feat[s3];
        a0 += f0.x + f1.x + f2.x + f3.x;
        a1 += f0.y + f1.y + f2.y + f3.y;
        a2 += f0.z + f1.z + f2.z + f3.z;
        a3 += f0.w + f1.w + f2.w + f3.w;
    }
    for (; j < c; ++j) {
        float4 f = feat[srtd[idx + j]];
        a0 += f.x; a1 += f.y; a2 += f.z; a3 += f.w;
    }
    return make_float4(a0, a1, a2, a3);
}

// fp16 run gather from global, 4-sweep src-quartering (R10): per-sweep
// working set 2 MB (quarter of 8 MB table) -> L2-resident. Index run is
// one cache line per thread, re-read 4x from L1/L2 (cheap).
__device__ __forceinline__ float4 run_sum4h_swept(
    const unsigned* __restrict__ srtd, unsigned idx, unsigned c,
    const ushort4* __restrict__ feat)
{
    float a0 = 0, a1 = 0, a2 = 0, a3 = 0;
#pragma unroll 1
    for (unsigned q = 0; q < 4; ++q) {
        for (unsigned j = 0; j < c; ++j) {
            unsigned s = srtd[idx + j];
            if ((s >> 18) == q) {
                float4 f = unpack_h4(feat[s]);
                a0 += f.x; a1 += f.y; a2 += f.z; a3 += f.w;
            }
        }
    }
    return make_float4(a0, a1, a2, a3);
}

template <bool USE16>
__global__ __launch_bounds__(256) void agg_l2(
    const unsigned* __restrict__ srtd, const unsigned* __restrict__ meta,
    const float4* __restrict__ h1, const ushort4* __restrict__ h1h,
    const float* __restrict__ inv,
    const float* __restrict__ W2l, const float* __restrict__ b2,
    const float* __restrict__ W2r,
    float4* __restrict__ h2, ushort4* __restrict__ h2h, int N)
{
    int dst = blockIdx.x * 256 + threadIdx.x;
    if (dst >= N) return;
    unsigned m = meta[dst];
    unsigned gidx = (unsigned)blockIdx.x * CAP + (m & 0xffffu);
    unsigned c = m >> 16;
    float4 s4 = USE16 ? run_sum4h_swept(srtd, gidx, c, h1h)
                      : run_sum4      (srtd, gidx, c, h1);
    float iv = inv[dst];
    float a[4] = {s4.x * iv, s4.y * iv, s4.z * iv, s4.w * iv};
    float4 hv = h1[dst];                 // self-path: fp32, sequential
    float hr[4] = {hv.x, hv.y, hv.z, hv.w};
    float o[4];
#pragma unroll
    for (int j = 0; j < 4; ++j) {
        float acc = b2[j];
#pragma unroll
        for (int k = 0; k < 4; ++k)
            acc += a[k] * W2l[k * 4 + j] + hr[k] * W2r[k * 4 + j];
        o[j] = fmaxf(acc, 0.0f);
    }
    float4 h = make_float4(o[0], o[1], o[2], o[3]);
    h2[dst] = h;
    if (USE16) h2h[dst] = pack_h4(h);
}

template <bool USE16>
__global__ __launch_bounds__(256) void agg_l3(
    const unsigned* __restrict__ srtd, const unsigned* __restrict__ meta,
    const float4* __restrict__ h2, const ushort4* __restrict__ h2h,
    const float* __restrict__ inv,
    const float* __restrict__ W3l, const float* __restrict__ b3,
    const float* __restrict__ W3r,
    const float* __restrict__ Wc, const float* __restrict__ bc,
    float2* __restrict__ out, float2* __restrict__ hout, int N)
{
    int dst = blockIdx.x * 256 + threadIdx.x;
    if (dst >= N) return;
    unsigned m = meta[dst];
    unsigned gidx = (unsigned)blockIdx.x * CAP + (m & 0xffffu);
    unsigned c = m >> 16;
    float4 s4 = USE16 ? run_sum4h_swept(srtd, gidx, c, h2h)
                      : run_sum4      (srtd, gidx, c, h2);
    float iv = inv[dst];
    float a[4] = {s4.x * iv, s4.y * iv, s4.z * iv, s4.w * iv};
    float4 hv = h2[dst];
    float hr[4] = {hv.x, hv.y, hv.z, hv.w};
    float h3[2];
#pragma unroll
    for (int j = 0; j < 2; ++j) {
        float acc = b3[j];
#pragma unroll
        for (int k = 0; k < 4; ++k)
            acc += a[k] * W3l[k * 2 + j] + hr[k] * W3r[k * 2 + j];
        h3[j] = fmaxf(acc, 0.0f);
    }
    float o0 = h3[0] * Wc[0] + h3[1] * Wc[2] + bc[0];
    float o1 = h3[0] * Wc[1] + h3[1] * Wc[3] + bc[1];
    out[dst]  = make_float2(o0, o1);
    hout[dst] = make_float2(h3[0], h3[1]);
}

// ------------------------------------------------- fallback path (round 3)
#define FPS   262144.0f
#define IFPS  3.8146973e-06f
#define XBIAS 16.0f

__global__ __launch_bounds__(256) void edge_pass1(
    const int* __restrict__ ei, const float* __restrict__ x,
    unsigned long long* __restrict__ agg1, long long E)
{
    long long i = (long long)blockIdx.x * blockDim.x + threadIdx.x;
    const long long stride = (long long)gridDim.x * blockDim.x;
    for (; i < E; i += stride) {
        int s = ei[i];
        int d = ei[E + i];
        unsigned q = (unsigned)((x[s] + XBIAS) * FPS + 0.5f);
        atomicAdd(&agg1[d], (unsigned long long)q | (1ull << 32));
    }
}

__global__ __launch_bounds__(256) void edge_pass4(
    const int* __restrict__ ei, const float4* __restrict__ feat,
    unsigned long long* __restrict__ pair, long long E)
{
    long long i = (long long)blockIdx.x * blockDim.x + threadIdx.x;
    const long long stride = (long long)gridDim.x * blockDim.x;
    for (; i < E; i += stride) {
        int s = ei[i];
        int d = ei[E + i];
        float4 f = feat[s];
        unsigned q0 = (unsigned)(f.x * FPS + 0.5f);
        unsigned q1 = (unsigned)(f.y * FPS + 0.5f);
        unsigned q2 = (unsigned)(f.z * FPS + 0.5f);
        unsigned q3 = (unsigned)(f.w * FPS + 0.5f);
        atomicAdd(&pair[2ll*d+0], (unsigned long long)q0 | ((unsigned long long)q1 << 32));
        atomicAdd(&pair[2ll*d+1], (unsigned long long)q2 | ((unsigned long long)q3 << 32));
    }
}

__global__ __launch_bounds__(256) void node_pass1(
    const float* __restrict__ x, const unsigned long long* __restrict__ agg1,
    float* __restrict__ invout, const float* __restrict__ W1l,
    const float* __restrict__ b1, const float* __restrict__ W1r,
    float4* __restrict__ h1, int N)
{
    int i = blockIdx.x * blockDim.x + threadIdx.x;
    if (i >= N) return;
    unsigned long long v = agg1[i];
    float cnt = (float)(unsigned)(v >> 32);
    float lo  = (float)(unsigned)(v & 0xffffffffu);
    float sumx = lo * IFPS - XBIAS * cnt;
    float inv = 1.0f / fmaxf(cnt, 1.0f);
    invout[i] = inv;
    float a = sumx * inv;
    float xv = x[i];
    float4 h;
    h.x = fmaxf(a * W1l[0] + b1[0] + xv * W1r[0], 0.0f);
    h.y = fmaxf(a * W1l[1] + b1[1] + xv * W1r[1], 0.0f);
    h.z = fmaxf(a * W1l[2] + b1[2] + xv * W1r[2], 0.0f);
    h.w = fmaxf(a * W1l[3] + b1[3] + xv * W1r[3], 0.0f);
    h1[i] = h;
}

__device__ __forceinline__ float4 unpack_agg(const unsigned long long* pair, int i, float iv)
{
    unsigned long long m01 = pair[2ll * i + 0];
    unsigned long long m23 = pair[2ll * i + 1];
    float4 a;
    a.x = (float)(unsigned)(m01 & 0xffffffffu) * IFPS * iv;
    a.y = (float)(unsigned)(m01 >> 32)         * IFPS * iv;
    a.z = (float)(unsigned)(m23 & 0xffffffffu) * IFPS * iv;
    a.w = (float)(unsigned)(m23 >> 32)         * IFPS * iv;
    return a;
}

__global__ __launch_bounds__(256) void node_pass2(
    const unsigned long long* __restrict__ pair, const float4* __restrict__ h1,
    const float* __restrict__ inv, const float* __restrict__ W2l,
    const float* __restrict__ b2, const float* __restrict__ W2r,
    float4* __restrict__ h2, int N)
{
    int i = blockIdx.x * blockDim.x + threadIdx.x;
    if (i >= N) return;
    float iv = inv[i];
    float4 ag = unpack_agg(pair, i, iv);
    float4 hv = h1[i];
    float a[4]  = {ag.x, ag.y, ag.z, ag.w};
    float hr[4] = {hv.x, hv.y, hv.z, hv.w};
    float o[4];
#pragma unroll
    for (int j = 0; j < 4; ++j) {
        float acc = b2[j];
#pragma unroll
        for (int k = 0; k < 4; ++k)
            acc += a[k] * W2l[k * 4 + j] + hr[k] * W2r[k * 4 + j];
        o[j] = fmaxf(acc, 0.0f);
    }
    h2[i] = make_float4(o[0], o[1], o[2], o[3]);
}

__global__ __launch_bounds__(256) void node_pass3(
    const unsigned long long* __restrict__ pair, const float4* __restrict__ h2,
    const float* __restrict__ inv, const float* __restrict__ W3l,
    const float* __restrict__ b3, const float* __restrict__ W3r,
    const float* __restrict__ Wc, const float* __restrict__ bc,
    float2* __restrict__ out, float2* __restrict__ hout, int N)
{
    int i = blockIdx.x * blockDim.x + threadIdx.x;
    if (i >= N) return;
    float iv = inv[i];
    float4 ag = unpack_agg(pair, i, iv);
    float4 hv = h2[i];
    float a[4]  = {ag.x, ag.y, ag.z, ag.w};
    float hr[4] = {hv.x, hv.y, hv.z, hv.w};
    float h3[2];
#pragma unroll
    for (int j = 0; j < 2; ++j) {
        float acc = b3[j];
#pragma unroll
        for (int k = 0; k < 4; ++k)
            acc += a[k] * W3l[k * 2 + j] + hr[k] * W3r[k * 2 + j];
        h3[j] = fmaxf(acc, 0.0f);
    }
    float o0 = h3[0] * Wc[0] + h3[1] * Wc[2] + bc[0];
    float o1 = h3[0] * Wc[1] + h3[1] * Wc[3] + bc[1];
    out[i]  = make_float2(o0, o1);
    hout[i] = make_float2(h3[0], h3[1]);
}

// ---------------------------------------------------------------- launch
extern "C" void kernel_launch(void* const* d_in, const int* in_sizes, int n_in,
                              void* d_out, int out_size, void* d_ws, size_t ws_size,
                              hipStream_t stream)
{
    const float* x   = (const float*)d_in[0];
    const int*   ei  = (const int*)d_in[1];          // int32 [2, E]
    const float* W1l = (const float*)d_in[2];
    const float* b1  = (const float*)d_in[3];
    const float* W1r = (const float*)d_in[4];
    const float* W2l = (const float*)d_in[5];
    const float* b2  = (const float*)d_in[6];
    const float* W2r = (const float*)d_in[7];
    const float* W3l = (const float*)d_in[8];
    const float* b3  = (const float*)d_in[9];
    const float* W3r = (const float*)d_in[10];
    const float* Wc  = (const float*)d_in[11];
    const float* bc  = (const float*)d_in[12];

    const long long N = in_sizes[0];          // 1,000,000
    const long long E = in_sizes[1] / 2;      // 16,000,000

    float* out  = (float*)d_out;        // [N,2] logits
    float* hout = out + 2 * N;          // [N,2] h3

    // ws: [inv N][h1 4N][h2 4N][cursor][bucket][meta N] (+tail: [h1h 2N][h2h 2N])
    const size_t need_base =
        (size_t)(9 * N) * 4 + (size_t)NBUCK * 4 +
        (size_t)NBUCK * (size_t)CAP * 4 + (size_t)N * 4;
    const size_t need16 = need_base + (size_t)(4 * N) * 4;

    if (ws_size >= need_base) {
        float*    inv    = (float*)d_ws;
        float*    h1     = inv + N;
        float*    h2     = h1 + 4 * N;
        unsigned* cursor = (unsigned*)(h2 + 4 * N);
        unsigned* bucket = cursor + NBUCK;
        unsigned* meta   = bucket + (size_t)NBUCK * CAP;
        ushort4*  h1h    = (ushort4*)(meta + N);
        ushort4*  h2h    = h1h + N;
        const bool f16   = ws_size >= need16;

        const int SB = 512;                           // 2 blocks per CU
        long long chunk = (E + SB - 1) / SB;
        chunk = (chunk + 4095) & ~4095ll;
        const int nbk = (int)((N + 255) / 256);

        init_cursor<<<NBUCK / 256, 256, 0, stream>>>(cursor);
        scatter_staged<<<SB, 1024, 0, stream>>>(ei, cursor, bucket, E, chunk);
        if (f16) {
            sort_l1<true><<<nbk, 256, 0, stream>>>(bucket, cursor, meta, x,
                W1l, b1, W1r, inv, (float4*)h1, h1h, (int)N);
            agg_l2<true><<<nbk, 256, 0, stream>>>(bucket, meta,
                (const float4*)h1, h1h, inv, W2l, b2, W2r, (float4*)h2, h2h, (int)N);
            agg_l3<true><<<nbk, 256, 0, stream>>>(bucket, meta,
                (const float4*)h2, h2h, inv, W3l, b3, W3r, Wc, bc,
                (float2*)out, (float2*)hout, (int)N);
        } else {
            sort_l1<false><<<nbk, 256, 0, stream>>>(bucket, cursor, meta, x,
                W1l, b1, W1r, inv, (float4*)h1, nullptr, (int)N);
            agg_l2<false><<<nbk, 256, 0, stream>>>(bucket, meta,
                (const float4*)h1, nullptr, inv, W2l, b2, W2r, (float4*)h2, nullptr, (int)N);
            agg_l3<false><<<nbk, 256, 0, stream>>>(bucket, meta,
                (const float4*)h2, nullptr, inv, W3l, b3, W3r, Wc, bc,
                (float2*)out, (float2*)hout, (int)N);
        }
        return;
    }

    // Fallback: round-3 packed-atomic path (52 MB ws)
    float* ws  = (float*)d_ws;
    float* inv = ws;
    float* h1  = inv + N;
    unsigned long long* pair = (unsigned long long*)(h1 + 4 * N);
    float* h2  = (float*)(pair + 2 * N);

    const int nt = 256, eb = 8192;
    const int nb = (int)((N + nt - 1) / nt);

    hipMemsetAsync(pair, 0, (size_t)N * sizeof(unsigned long long), stream);
    edge_pass1<<<eb, nt, 0, stream>>>(ei, x, pair, E);
    node_pass1<<<nb, nt, 0, stream>>>(x, pair, inv, W1l, b1, W1r, (float4*)h1, (int)N);

    hipMemsetAsync(pair, 0, (size_t)(2 * N) * sizeof(unsigned long long), stream);
    edge_pass4<<<eb, nt, 0, stream>>>(ei, (const float4*)h1, pair, E);
    node_pass2<<<nb, nt, 0, stream>>>(pair, (const float4*)h1, inv,
                                      W2l, b2, W2r, (float4*)h2, (int)N);

    hipMemsetAsync(pair, 0, (size_t)(2 * N) * sizeof(unsigned long long), stream);
    edge_pass4<<<eb, nt, 0, stream>>>(ei, (const float4*)h2, pair, E);
    node_pass3<<<nb, nt, 0, stream>>>(pair, (const float4*)h2, inv,
                                      W3l, b3, W3r, Wc, bc,
                                      (float2*)out, (float2*)hout, (int)N);
}

// Round 15
// 620.482 us; speedup vs baseline: 2.1633x; 2.1633x over previous
//
#include <hip/hip_runtime.h>
#include <hip/hip_fp16.h>

// GraphSAGE 3-layer, N=1M, E=16M, widths 1->4->4->2.
// R3: device atomics limit. R4: bucketing. R5: counting sort + register agg.
// R7: LDS fill-and-flush scatter. R9: fp16 gather tables. R10: L2-resident
// gathers via 4-sweep src-quartering (LDS-staged runs). R11: scatter
// occupancy 2 blk/CU -> 623us BEST.
// R12 (quarter-keyed sort) regressed 681. R13 (dropped LDS srun) regressed
// 1342 - the sweep re-scan must come from LDS, not global.
// R14 (this): exact R11 revert.

#define NBUCK 4096
#define CAP   4608            // avg 4096 edges/bucket, +8 sigma headroom
#define SRCM  0xFFFFFu        // 20-bit src mask (N <= 2^20)
#define DEPTH 4               // staging slots per bucket (16 B group)

__device__ __forceinline__ ushort4 pack_h4(float4 f)
{
    ushort4 r;
    r.x = __half_as_ushort(__float2half_rn(f.x));
    r.y = __half_as_ushort(__float2half_rn(f.y));
    r.z = __half_as_ushort(__float2half_rn(f.z));
    r.w = __half_as_ushort(__float2half_rn(f.w));
    return r;
}

__device__ __forceinline__ float4 unpack_h4(ushort4 v)
{
    return make_float4(__half2float(__ushort_as_half(v.x)),
                       __half2float(__ushort_as_half(v.y)),
                       __half2float(__ushort_as_half(v.z)),
                       __half2float(__ushort_as_half(v.w)));
}

__global__ __launch_bounds__(256) void init_cursor(unsigned* __restrict__ cursor)
{
    int b = blockIdx.x * blockDim.x + threadIdx.x;
    if (b < NBUCK) cursor[b] = (unsigned)b * CAP;
}

// LDS fill-and-flush scatter: 80 KB LDS -> 2 blocks/CU.
__global__ __launch_bounds__(1024) void scatter_staged(
    const int* __restrict__ ei,
    unsigned* __restrict__ gcur,
    unsigned* __restrict__ bucket,
    long long E, long long chunk)
{
    __shared__ unsigned stage[NBUCK * DEPTH];  // 64 KB
    __shared__ unsigned cnt[NBUCK];            // 16 KB
    const int t = threadIdx.x;
    const long long beg = (long long)blockIdx.x * chunk;
    const long long end = min(E, beg + chunk);

    for (int i = t; i < NBUCK; i += 1024) cnt[i] = 0;
    __syncthreads();

    for (long long base = beg; base < end; base += 4096) {
        unsigned rec[4], bk[4], pos[4];
        int nv = 0;
        long long i = base + (long long)t * 4;
        if (i + 4 <= end) {
            int4 s4 = *reinterpret_cast<const int4*>(ei + i);
            int4 d4 = *reinterpret_cast<const int4*>(ei + E + i);
            rec[0] = (unsigned)s4.x | (((unsigned)d4.x & 255u) << 20); bk[0] = (unsigned)d4.x >> 8;
            rec[1] = (unsigned)s4.y | (((unsigned)d4.y & 255u) << 20); bk[1] = (unsigned)d4.y >> 8;
            rec[2] = (unsigned)s4.z | (((unsigned)d4.z & 255u) << 20); bk[2] = (unsigned)d4.z >> 8;
            rec[3] = (unsigned)s4.w | (((unsigned)d4.w & 255u) << 20); bk[3] = (unsigned)d4.w >> 8;
            nv = 4;
        } else {
            for (long long j = i; j < end && nv < 4; ++j) {
                unsigned s = (unsigned)ei[j];
                unsigned d = (unsigned)ei[E + j];
                rec[nv] = s | ((d & 255u) << 20);
                bk[nv] = d >> 8;
                ++nv;
            }
        }
        for (int k = 0; k < nv; ++k) pos[k] = atomicAdd(&cnt[bk[k]], 1u);
        __syncthreads();
        for (int k = 0; k < nv; ++k)
            if (pos[k] < DEPTH) stage[bk[k] * DEPTH + pos[k]] = rec[k];
        __syncthreads();
        // flush full buffers: one uint4 (16 B, aligned) per group
        for (int bb = t; bb < NBUCK; bb += 1024) {
            unsigned c = cnt[bb];
            if (c >= DEPTH) {
                unsigned gb = atomicAdd(&gcur[bb], DEPTH);
                unsigned lim = (unsigned)(bb + 1) * CAP;
                if ((gb & 3u) == 0u && gb + DEPTH <= lim) {
                    *reinterpret_cast<uint4*>(bucket + gb) =
                        *reinterpret_cast<const uint4*>(stage + bb * DEPTH);
                } else {
#pragma unroll
                    for (int k = 0; k < DEPTH; ++k)
                        if (gb + k < lim) bucket[gb + k] = stage[bb * DEPTH + k];
                }
                cnt[bb] = 0;
            }
        }
        __syncthreads();
        // round 2: records that overflowed the buffer this batch
        for (int k = 0; k < nv; ++k) {
            if (pos[k] >= DEPTH) {
                unsigned p2 = atomicAdd(&cnt[bk[k]], 1u);
                if (p2 < DEPTH) stage[bk[k] * DEPTH + p2] = rec[k];
                else {
                    unsigned gb = atomicAdd(&gcur[bk[k]], 1u);
                    if (gb < (unsigned)(bk[k] + 1) * CAP) bucket[gb] = rec[k];
                }
            }
        }
        __syncthreads();
    }
    // drain partial buffers
    for (int bb = t; bb < NBUCK; bb += 1024) {
        unsigned c = min(cnt[bb], (unsigned)DEPTH);
        if (c) {
            unsigned gb = atomicAdd(&gcur[bb], c);
            unsigned lim = (unsigned)(bb + 1) * CAP;
            for (unsigned k = 0; k < c; ++k)
                if (gb + k < lim) bucket[gb + k] = stage[bb * DEPTH + k];
        }
    }
}

// Fused: per-bucket 256-bin counting sort by dst + layer-1.
template <bool EMIT16>
__global__ __launch_bounds__(256) void sort_l1(
    unsigned* __restrict__ bucket,
    const unsigned* __restrict__ cursor,
    unsigned* __restrict__ meta,         // [N]: lstart | cnt<<16
    const float* __restrict__ x,
    const float* __restrict__ W1l, const float* __restrict__ b1,
    const float* __restrict__ W1r,
    float* __restrict__ invout, float4* __restrict__ h1,
    ushort4* __restrict__ h1h, int N)
{
    __shared__ unsigned recA[CAP];
    __shared__ unsigned recB[CAP];
    __shared__ unsigned hist[256], pref[256], curs[256];
    const int t = threadIdx.x;
    const unsigned b = blockIdx.x;
    const unsigned base = b * CAP;
    const unsigned cnt = min(cursor[b] - base, (unsigned)CAP);

    hist[t] = 0;
    __syncthreads();
    for (unsigned i = t; i < cnt; i += 256) {
        unsigned r = bucket[base + i];
        recA[i] = r;
        atomicAdd(&hist[r >> 20], 1u);
    }
    __syncthreads();
    unsigned v = hist[t];
    pref[t] = v;
    __syncthreads();
    for (int off = 1; off < 256; off <<= 1) {
        unsigned u = (t >= off) ? pref[t - off] : 0u;
        __syncthreads();
        pref[t] += u;
        __syncthreads();
    }
    unsigned excl = pref[t] - v;
    curs[t] = excl;
    __syncthreads();
    for (unsigned i = t; i < cnt; i += 256) {
        unsigned r = recA[i];
        unsigned pos = atomicAdd(&curs[r >> 20], 1u);
        recB[pos] = r & SRCM;
    }
    __syncthreads();
    for (unsigned i = t; i < cnt; i += 256)
        bucket[base + i] = recB[i];

    int dst = (int)(b * 256u) + t;
    if (dst >= N) return;
    meta[dst] = excl | (v << 16);

    float sum = 0.0f;
    for (unsigned j = 0; j < v; ++j)
        sum += x[recB[excl + j]];
    float iv = 1.0f / fmaxf((float)v, 1.0f);
    invout[dst] = iv;
    float a = sum * iv;
    float xv = x[dst];
    float4 h;
    h.x = fmaxf(a * W1l[0] + b1[0] + xv * W1r[0], 0.0f);
    h.y = fmaxf(a * W1l[1] + b1[1] + xv * W1r[1], 0.0f);
    h.z = fmaxf(a * W1l[2] + b1[2] + xv * W1r[2], 0.0f);
    h.w = fmaxf(a * W1l[3] + b1[3] + xv * W1r[3], 0.0f);
    h1[dst] = h;
    if (EMIT16) h1h[dst] = pack_h4(h);
}

// fp32 run gather (non-fp16 fallback)
__device__ __forceinline__ float4 run_sum4(
    const unsigned* srtd, unsigned idx, unsigned c,
    const float4* __restrict__ feat)
{
    float a0 = 0, a1 = 0, a2 = 0, a3 = 0;
    unsigned j = 0;
    for (; j + 4 <= c; j += 4) {
        unsigned s0 = srtd[idx + j + 0];
        unsigned s1 = srtd[idx + j + 1];
        unsigned s2 = srtd[idx + j + 2];
        unsigned s3 = srtd[idx + j + 3];
        float4 f0 = feat[s0];
        float4 f1 = feat[s1];
        float4 f2 = feat[s2];
        float4 f3 = feat[s3];
        a0 += f0.x + f1.x + f2.x + f3.x;
        a1 += f0.y + f1.y + f2.y + f3.y;
        a2 += f0.z + f1.z + f2.z + f3.z;
        a3 += f0.w + f1.w + f2.w + f3.w;
    }
    for (; j < c; ++j) {
        float4 f = feat[srtd[idx + j]];
        a0 += f.x; a1 += f.y; a2 += f.z; a3 += f.w;
    }
    return make_float4(a0, a1, a2, a3);
}

// fp16 run gather, 4-sweep src-quartering from LDS-staged runs: per-sweep
// gather working set 2 MB (quarter of the 8 MB table) -> L2-resident.
__device__ __forceinline__ float4 run_sum4h_swept(
    const unsigned* srun, unsigned idx, unsigned c,
    const ushort4* __restrict__ feat)
{
    float a0 = 0, a1 = 0, a2 = 0, a3 = 0;
#pragma unroll 1
    for (unsigned q = 0; q < 4; ++q) {
        for (unsigned j = 0; j < c; ++j) {
            unsigned s = srun[idx + j];
            if ((s >> 18) == q) {
                float4 f = unpack_h4(feat[s]);
                a0 += f.x; a1 += f.y; a2 += f.z; a3 += f.w;
            }
        }
    }
    return make_float4(a0, a1, a2, a3);
}

template <bool USE16>
__global__ __launch_bounds__(256) void agg_l2(
    const unsigned* __restrict__ srtd, const unsigned* __restrict__ cursor,
    const unsigned* __restrict__ meta,
    const float4* __restrict__ h1, const ushort4* __restrict__ h1h,
    const float* __restrict__ inv,
    const float* __restrict__ W2l, const float* __restrict__ b2,
    const float* __restrict__ W2r,
    float4* __restrict__ h2, ushort4* __restrict__ h2h, int N)
{
    __shared__ unsigned srun[CAP];       // 18 KB
    const int t = threadIdx.x;
    const unsigned b = blockIdx.x;
    const unsigned base = b * CAP;
    const unsigned bc = min(cursor[b] - base, (unsigned)CAP);
    for (unsigned i = t; i < bc; i += 256) srun[i] = srtd[base + i];
    __syncthreads();

    int dst = (int)(b * 256u) + t;
    if (dst >= N) return;
    unsigned m = meta[dst];
    float4 s4 = USE16 ? run_sum4h_swept(srun, m & 0xffffu, m >> 16, h1h)
                      : run_sum4      (srun, m & 0xffffu, m >> 16, h1);
    float iv = inv[dst];
    float a[4] = {s4.x * iv, s4.y * iv, s4.z * iv, s4.w * iv};
    float4 hv = h1[dst];                 // self-path: fp32, sequential
    float hr[4] = {hv.x, hv.y, hv.z, hv.w};
    float o[4];
#pragma unroll
    for (int j = 0; j < 4; ++j) {
        float acc = b2[j];
#pragma unroll
        for (int k = 0; k < 4; ++k)
            acc += a[k] * W2l[k * 4 + j] + hr[k] * W2r[k * 4 + j];
        o[j] = fmaxf(acc, 0.0f);
    }
    float4 h = make_float4(o[0], o[1], o[2], o[3]);
    h2[dst] = h;
    if (USE16) h2h[dst] = pack_h4(h);
}

template <bool USE16>
__global__ __launch_bounds__(256) void agg_l3(
    const unsigned* __restrict__ srtd, const unsigned* __restrict__ cursor,
    const unsigned* __restrict__ meta,
    const float4* __restrict__ h2, const ushort4* __restrict__ h2h,
    const float* __restrict__ inv,
    const float* __restrict__ W3l, const float* __restrict__ b3,
    const float* __restrict__ W3r,
    const float* __restrict__ Wc, const float* __restrict__ bc,
    float2* __restrict__ out, float2* __restrict__ hout, int N)
{
    __shared__ unsigned srun[CAP];
    const int t = threadIdx.x;
    const unsigned b = blockIdx.x;
    const unsigned base = b * CAP;
    const unsigned bcnt = min(cursor[b] - base, (unsigned)CAP);
    for (unsigned i = t; i < bcnt; i += 256) srun[i] = srtd[base + i];
    __syncthreads();

    int dst = (int)(b * 256u) + t;
    if (dst >= N) return;
    unsigned m = meta[dst];
    float4 s4 = USE16 ? run_sum4h_swept(srun, m & 0xffffu, m >> 16, h2h)
                      : run_sum4      (srun, m & 0xffffu, m >> 16, h2);
    float iv = inv[dst];
    float a[4] = {s4.x * iv, s4.y * iv, s4.z * iv, s4.w * iv};
    float4 hv = h2[dst];
    float hr[4] = {hv.x, hv.y, hv.z, hv.w};
    float h3[2];
#pragma unroll
    for (int j = 0; j < 2; ++j) {
        float acc = b3[j];
#pragma unroll
        for (int k = 0; k < 4; ++k)
            acc += a[k] * W3l[k * 2 + j] + hr[k] * W3r[k * 2 + j];
        h3[j] = fmaxf(acc, 0.0f);
    }
    float o0 = h3[0] * Wc[0] + h3[1] * Wc[2] + bc[0];
    float o1 = h3[0] * Wc[1] + h3[1] * Wc[3] + bc[1];
    out[dst]  = make_float2(o0, o1);
    hout[dst] = make_float2(h3[0], h3[1]);
}

// ------------------------------------------------- fallback path (round 3)
#define FPS   262144.0f
#define IFPS  3.8146973e-06f
#define XBIAS 16.0f

__global__ __launch_bounds__(256) void edge_pass1(
    const int* __restrict__ ei, const float* __restrict__ x,
    unsigned long long* __restrict__ agg1, long long E)
{
    long long i = (long long)blockIdx.x * blockDim.x + threadIdx.x;
    const long long stride = (long long)gridDim.x * blockDim.x;
    for (; i < E; i += stride) {
        int s = ei[i];
        int d = ei[E + i];
        unsigned q = (unsigned)((x[s] + XBIAS) * FPS + 0.5f);
        atomicAdd(&agg1[d], (unsigned long long)q | (1ull << 32));
    }
}

__global__ __launch_bounds__(256) void edge_pass4(
    const int* __restrict__ ei, const float4* __restrict__ feat,
    unsigned long long* __restrict__ pair, long long E)
{
    long long i = (long long)blockIdx.x * blockDim.x + threadIdx.x;
    const long long stride = (long long)gridDim.x * blockDim.x;
    for (; i < E; i += stride) {
        int s = ei[i];
        int d = ei[E + i];
        float4 f = feat[s];
        unsigned q0 = (unsigned)(f.x * FPS + 0.5f);
        unsigned q1 = (unsigned)(f.y * FPS + 0.5f);
        unsigned q2 = (unsigned)(f.z * FPS + 0.5f);
        unsigned q3 = (unsigned)(f.w * FPS + 0.5f);
        atomicAdd(&pair[2ll*d+0], (unsigned long long)q0 | ((unsigned long long)q1 << 32));
        atomicAdd(&pair[2ll*d+1], (unsigned long long)q2 | ((unsigned long long)q3 << 32));
    }
}

__global__ __launch_bounds__(256) void node_pass1(
    const float* __restrict__ x, const unsigned long long* __restrict__ agg1,
    float* __restrict__ invout, const float* __restrict__ W1l,
    const float* __restrict__ b1, const float* __restrict__ W1r,
    float4* __restrict__ h1, int N)
{
    int i = blockIdx.x * blockDim.x + threadIdx.x;
    if (i >= N) return;
    unsigned long long v = agg1[i];
    float cnt = (float)(unsigned)(v >> 32);
    float lo  = (float)(unsigned)(v & 0xffffffffu);
    float sumx = lo * IFPS - XBIAS * cnt;
    float inv = 1.0f / fmaxf(cnt, 1.0f);
    invout[i] = inv;
    float a = sumx * inv;
    float xv = x[i];
    float4 h;
    h.x = fmaxf(a * W1l[0] + b1[0] + xv * W1r[0], 0.0f);
    h.y = fmaxf(a * W1l[1] + b1[1] + xv * W1r[1], 0.0f);
    h.z = fmaxf(a * W1l[2] + b1[2] + xv * W1r[2], 0.0f);
    h.w = fmaxf(a * W1l[3] + b1[3] + xv * W1r[3], 0.0f);
    h1[i] = h;
}

__device__ __forceinline__ float4 unpack_agg(const unsigned long long* pair, int i, float iv)
{
    unsigned long long m01 = pair[2ll * i + 0];
    unsigned long long m23 = pair[2ll * i + 1];
    float4 a;
    a.x = (float)(unsigned)(m01 & 0xffffffffu) * IFPS * iv;
    a.y = (float)(unsigned)(m01 >> 32)         * IFPS * iv;
    a.z = (float)(unsigned)(m23 & 0xffffffffu) * IFPS * iv;
    a.w = (float)(unsigned)(m23 >> 32)         * IFPS * iv;
    return a;
}

__global__ __launch_bounds__(256) void node_pass2(
    const unsigned long long* __restrict__ pair, const float4* __restrict__ h1,
    const float* __restrict__ inv, const float* __restrict__ W2l,
    const float* __restrict__ b2, const float* __restrict__ W2r,
    float4* __restrict__ h2, int N)
{
    int i = blockIdx.x * blockDim.x + threadIdx.x;
    if (i >= N) return;
    float iv = inv[i];
    float4 ag = unpack_agg(pair, i, iv);
    float4 hv = h1[i];
    float a[4]  = {ag.x, ag.y, ag.z, ag.w};
    float hr[4] = {hv.x, hv.y, hv.z, hv.w};
    float o[4];
#pragma unroll
    for (int j = 0; j < 4; ++j) {
        float acc = b2[j];
#pragma unroll
        for (int k = 0; k < 4; ++k)
            acc += a[k] * W2l[k * 4 + j] + hr[k] * W2r[k * 4 + j];
        o[j] = fmaxf(acc, 0.0f);
    }
    h2[i] = make_float4(o[0], o[1], o[2], o[3]);
}

__global__ __launch_bounds__(256) void node_pass3(
    const unsigned long long* __restrict__ pair, const float4* __restrict__ h2,
    const float* __restrict__ inv, const float* __restrict__ W3l,
    const float* __restrict__ b3, const float* __restrict__ W3r,
    const float* __restrict__ Wc, const float* __restrict__ bc,
    float2* __restrict__ out, float2* __restrict__ hout, int N)
{
    int i = blockIdx.x * blockDim.x + threadIdx.x;
    if (i >= N) return;
    float iv = inv[i];
    float4 ag = unpack_agg(pair, i, iv);
    float4 hv = h2[i];
    float a[4]  = {ag.x, ag.y, ag.z, ag.w};
    float hr[4] = {hv.x, hv.y, hv.z, hv.w};
    float h3[2];
#pragma unroll
    for (int j = 0; j < 2; ++j) {
        float acc = b3[j];
#pragma unroll
        for (int k = 0; k < 4; ++k)
            acc += a[k] * W3l[k * 2 + j] + hr[k] * W3r[k * 2 + j];
        h3[j] = fmaxf(acc, 0.0f);
    }
    float o0 = h3[0] * Wc[0] + h3[1] * Wc[2] + bc[0];
    float o1 = h3[0] * Wc[1] + h3[1] * Wc[3] + bc[1];
    out[i]  = make_float2(o0, o1);
    hout[i] = make_float2(h3[0], h3[1]);
}

// ---------------------------------------------------------------- launch
extern "C" void kernel_launch(void* const* d_in, const int* in_sizes, int n_in,
                              void* d_out, int out_size, void* d_ws, size_t ws_size,
                              hipStream_t stream)
{
    const float* x   = (const float*)d_in[0];
    const int*   ei  = (const int*)d_in[1];          // int32 [2, E]
    const float* W1l = (const float*)d_in[2];
    const float* b1  = (const float*)d_in[3];
    const float* W1r = (const float*)d_in[4];
    const float* W2l = (const float*)d_in[5];
    const float* b2  = (const float*)d_in[6];
    const float* W2r = (const float*)d_in[7];
    const float* W3l = (const float*)d_in[8];
    const float* b3  = (const float*)d_in[9];
    const float* W3r = (const float*)d_in[10];
    const float* Wc  = (const float*)d_in[11];
    const float* bc  = (const float*)d_in[12];

    const long long N = in_sizes[0];          // 1,000,000
    const long long E = in_sizes[1] / 2;      // 16,000,000

    float* out  = (float*)d_out;        // [N,2] logits
    float* hout = out + 2 * N;          // [N,2] h3

    // ws: [inv N][h1 4N][h2 4N][cursor][bucket][meta N] (+tail: [h1h 2N][h2h 2N])
    const size_t need_base =
        (size_t)(9 * N) * 4 + (size_t)NBUCK * 4 +
        (size_t)NBUCK * (size_t)CAP * 4 + (size_t)N * 4;
    const size_t need16 = need_base + (size_t)(4 * N) * 4;

    if (ws_size >= need_base) {
        float*    inv    = (float*)d_ws;
        float*    h1     = inv + N;
        float*    h2     = h1 + 4 * N;
        unsigned* cursor = (unsigned*)(h2 + 4 * N);
        unsigned* bucket = cursor + NBUCK;
        unsigned* meta   = bucket + (size_t)NBUCK * CAP;
        ushort4*  h1h    = (ushort4*)(meta + N);
        ushort4*  h2h    = h1h + N;
        const bool f16   = ws_size >= need16;

        const int SB = 512;                           // 2 blocks per CU
        long long chunk = (E + SB - 1) / SB;
        chunk = (chunk + 4095) & ~4095ll;
        const int nbk = (int)((N + 255) / 256);

        init_cursor<<<NBUCK / 256, 256, 0, stream>>>(cursor);
        scatter_staged<<<SB, 1024, 0, stream>>>(ei, cursor, bucket, E, chunk);
        if (f16) {
            sort_l1<true><<<nbk, 256, 0, stream>>>(bucket, cursor, meta, x,
                W1l, b1, W1r, inv, (float4*)h1, h1h, (int)N);
            agg_l2<true><<<nbk, 256, 0, stream>>>(bucket, cursor, meta,
                (const float4*)h1, h1h, inv, W2l, b2, W2r, (float4*)h2, h2h, (int)N);
            agg_l3<true><<<nbk, 256, 0, stream>>>(bucket, cursor, meta,
                (const float4*)h2, h2h, inv, W3l, b3, W3r, Wc, bc,
                (float2*)out, (float2*)hout, (int)N);
        } else {
            sort_l1<false><<<nbk, 256, 0, stream>>>(bucket, cursor, meta, x,
                W1l, b1, W1r, inv, (float4*)h1, nullptr, (int)N);
            agg_l2<false><<<nbk, 256, 0, stream>>>(bucket, cursor, meta,
                (const float4*)h1, nullptr, inv, W2l, b2, W2r, (float4*)h2, nullptr, (int)N);
            agg_l3<false><<<nbk, 256, 0, stream>>>(bucket, cursor, meta,
                (const float4*)h2, nullptr, inv, W3l, b3, W3r, Wc, bc,
                (float2*)out, (float2*)hout, (int)N);
        }
        return;
    }

    // Fallback: round-3 packed-atomic path (52 MB ws)
    float* ws  = (float*)d_ws;
    float* inv = ws;
    float* h1  = inv + N;
    unsigned long long* pair = (unsigned long long*)(h1 + 4 * N);
    float* h2  = (float*)(pair + 2 * N);

    const int nt = 256, eb = 8192;
    const int nb = (int)((N + nt - 1) / nt);

    hipMemsetAsync(pair, 0, (size_t)N * sizeof(unsigned long long), stream);
    edge_pass1<<<eb, nt, 0, stream>>>(ei, x, pair, E);
    node_pass1<<<nb, nt, 0, stream>>>(x, pair, inv, W1l, b1, W1r, (float4*)h1, (int)N);

    hipMemsetAsync(pair, 0, (size_t)(2 * N) * sizeof(unsigned long long), stream);
    edge_pass4<<<eb, nt, 0, stream>>>(ei, (const float4*)h1, pair, E);
    node_pass2<<<nb, nt, 0, stream>>>(pair, (const float4*)h1, inv,
                                      W2l, b2, W2r, (float4*)h2, (int)N);

    hipMemsetAsync(pair, 0, (size_t)(2 * N) * sizeof(unsigned long long), stream);
    edge_pass4<<<eb, nt, 0, stream>>>(ei, (const float4*)h2, pair, E);
    node_pass3<<<nb, nt, 0, stream>>>(pair, (const float4*)h2, inv,
                                      W3l, b3, W3r, Wc, bc,
                                      (float2*)out, (float2*)hout, (int)N);
}